// Round 5
// baseline (682.038 us; speedup 1.0000x reference)
//
#include <hip/hip_runtime.h>

// ChannelAttention on MI355X (gfx950)
// B=128, HW=256, C=1024, S=32, EMB=256, IDF=256(==HW)
//
// out[b,p,c] = sum_s we[b,s,p] * softmax_s( sum_p' wc[b,p',c] * we[b,s,p'] )
// attn[b,c,s] = softmax probabilities
// d_out: out (128*256*1024 f32) then attn (128*1024*32 f32)
// d_ws : weT[b][p][s] (4 MB)
//
// R4 lesson chain: R1 (broadcast VMEM) and R0/R2/R3 (scalar-cache chains)
// show the wave-uniform weT operand is the stall source. This version makes
// EVERY operand a per-lane VMEM load: wave = 16 channels x 4 role-groups.
//  Phase A: lane=(c, s-octet): 8 acc; wc[p][c] per-lane + weT[p][oct] float4x2.
//  Softmax: 4-lane-group reduce via __shfl_xor(16,32).
//  P-gather: 32 bpermutes -> full 32-float P row per lane (static indexing).
//  Phase B: lane=(c, p-quarter): float4 weT reads, 32 FMA/p, coalesced store.
// No LDS in attn_kernel; 2048 blocks; ~60 VGPR -> ~6 waves/SIMD.

namespace {
constexpr int kB  = 128;
constexpr int kHW = 256;
constexpr int kC  = 1024;
constexpr int kS  = 32;
constexpr int kE  = 256;
}

// weT[b][p][s] = bias[p] + sum_e emb[b][s][e] * K[e][p]
// 512 thr = 2 e-halves x 256 p; grid (4,128); LDS combine of the two halves.
__global__ __launch_bounds__(512) void we_proj_kernel(
    const float* __restrict__ emb, const float* __restrict__ K,
    const float* __restrict__ bias, float* __restrict__ weT) {
  const int b  = blockIdx.y;
  const int sq = blockIdx.x;                 // 8 s-values per block
  const int p  = threadIdx.x & 255;
  const int eh = threadIdx.x >> 8;           // e-half: 0 or 1
  const float* embb = emb + (size_t)b * kS * kE + (size_t)sq * 8 * kE + eh * 128;
  const float* Kh   = K + (size_t)eh * 128 * kHW;

  __shared__ float part[256][8];

  float acc[8];
#pragma unroll
  for (int j = 0; j < 8; ++j) acc[j] = 0.f;

  float kA[8], kB2[8];
#pragma unroll
  for (int u = 0; u < 8; ++u) kA[u] = Kh[u * kHW + p];

  for (int e0 = 0; e0 < 128; e0 += 16) {
#pragma unroll
    for (int u = 0; u < 8; ++u) kB2[u] = Kh[(e0 + 8 + u) * kHW + p];
#pragma unroll
    for (int u = 0; u < 8; ++u) {
      const float kv = kA[u];
#pragma unroll
      for (int j = 0; j < 8; ++j)
        acc[j] = fmaf(embb[j * kE + e0 + u], kv, acc[j]);
    }
    if (e0 + 16 < 128) {
#pragma unroll
      for (int u = 0; u < 8; ++u) kA[u] = Kh[(e0 + 16 + u) * kHW + p];
    }
#pragma unroll
    for (int u = 0; u < 8; ++u) {
      const float kv = kB2[u];
#pragma unroll
      for (int j = 0; j < 8; ++j)
        acc[j] = fmaf(embb[j * kE + e0 + 8 + u], kv, acc[j]);
    }
  }

  if (eh == 1) {
#pragma unroll
    for (int j = 0; j < 8; ++j) part[p][j] = acc[j];
  }
  __syncthreads();
  if (eh == 0) {
    const float bv = bias[p];
#pragma unroll
    for (int j = 0; j < 8; ++j) acc[j] += part[p][j] + bv;
    float4* dst = (float4*)(weT + ((size_t)b * kHW + p) * kS + sq * 8);
    dst[0] = make_float4(acc[0], acc[1], acc[2], acc[3]);
    dst[1] = make_float4(acc[4], acc[5], acc[6], acc[7]);
  }
}

// grid (16,128), 256 thr = 4 waves; wave owns a 16-channel strip.
__global__ __launch_bounds__(256, 6) void attn_kernel(
    const float* __restrict__ wc, const float* __restrict__ weT,
    float* __restrict__ out, float* __restrict__ attn_out) {
  const int b    = blockIdx.y;
  const int wave = threadIdx.x >> 6;
  const int lane = threadIdx.x & 63;
  const int cl   = lane & 15;          // channel within strip
  const int grp  = lane >> 4;          // s-octet (A) / p-quarter (B)
  const int cb   = blockIdx.x * 64 + wave * 16;
  const int c    = cb + cl;

  const float* wcb_ = wc  + (size_t)b * kHW * kC;
  const float* weTb = weT + (size_t)b * kHW * kS;

  // ---- Phase A: acc[j] = logits[c][grp*8+j] ----
  float acc[8];
#pragma unroll
  for (int j = 0; j < 8; ++j) acc[j] = 0.f;

  const float* wcc = wcb_ + c;             // wc[p][c] = wcc[p*kC]
  const float* wts = weTb + grp * 8;       // weT[p][grp*8+j] = wts[p*kS+j]

#pragma unroll 4
  for (int p = 0; p < kHW; ++p) {
    const float w  = wcc[(size_t)p * kC];                   // per-lane, coalesced
    const float4 t0 = *(const float4*)(wts + p * kS);       // per-lane, L1/L2
    const float4 t1 = *(const float4*)(wts + p * kS + 4);
    acc[0] = fmaf(t0.x, w, acc[0]);
    acc[1] = fmaf(t0.y, w, acc[1]);
    acc[2] = fmaf(t0.z, w, acc[2]);
    acc[3] = fmaf(t0.w, w, acc[3]);
    acc[4] = fmaf(t1.x, w, acc[4]);
    acc[5] = fmaf(t1.y, w, acc[5]);
    acc[6] = fmaf(t1.z, w, acc[6]);
    acc[7] = fmaf(t1.w, w, acc[7]);
  }

  // ---- softmax over s: local 8 + cross-octet via shfl_xor(16,32) ----
  float m = acc[0];
#pragma unroll
  for (int j = 1; j < 8; ++j) m = fmaxf(m, acc[j]);
  m = fmaxf(m, __shfl_xor(m, 16));
  m = fmaxf(m, __shfl_xor(m, 32));
  float sum = 0.f;
#pragma unroll
  for (int j = 0; j < 8; ++j) {
    acc[j] = __expf(acc[j] - m);
    sum += acc[j];
  }
  sum += __shfl_xor(sum, 16);
  sum += __shfl_xor(sum, 32);
  const float inv = 1.0f / sum;
#pragma unroll
  for (int j = 0; j < 8; ++j) acc[j] *= inv;

  // ---- attn[b][c][grp*8 + j]: 32B per lane, 2KB contiguous per wave ----
  {
    float4* ap = (float4*)(attn_out + ((size_t)b * kC + c) * kS + grp * 8);
    ap[0] = make_float4(acc[0], acc[1], acc[2], acc[3]);
    ap[1] = make_float4(acc[4], acc[5], acc[6], acc[7]);
  }

  // ---- gather full P row (32 floats) per lane; static indexing ----
  float Pf[32];
#pragma unroll
  for (int o = 0; o < 4; ++o) {
    const int mask = (grp ^ o) << 4;     // per-lane mask -> ds_bpermute
#pragma unroll
    for (int j = 0; j < 8; ++j)
      Pf[o * 8 + j] = __shfl_xor(acc[j], mask);
  }

  // ---- Phase B: p in [grp*64, grp*64+64); out[p][c] ----
  float* outc = out + (size_t)b * kHW * kC + c;
  const float* wtr = weTb + (size_t)grp * 64 * kS;
#pragma unroll 2
  for (int pp = 0; pp < 64; ++pp) {
    const float* row = wtr + pp * kS;
    float o0 = 0.f, o1 = 0.f, o2 = 0.f, o3 = 0.f;
#pragma unroll
    for (int q = 0; q < 8; ++q) {
      const float4 v = *(const float4*)(row + q * 4);
      o0 = fmaf(v.x, Pf[q * 4 + 0], o0);
      o1 = fmaf(v.y, Pf[q * 4 + 1], o1);
      o2 = fmaf(v.z, Pf[q * 4 + 2], o2);
      o3 = fmaf(v.w, Pf[q * 4 + 3], o3);
    }
    outc[(size_t)(grp * 64 + pp) * kC] = (o0 + o1) + (o2 + o3);
  }
}

extern "C" void kernel_launch(void* const* d_in, const int* in_sizes, int n_in,
                              void* d_out, int out_size, void* d_ws, size_t ws_size,
                              hipStream_t stream) {
  const float* wc   = (const float*)d_in[0];
  const float* emb  = (const float*)d_in[1];
  const float* K    = (const float*)d_in[2];
  const float* bias = (const float*)d_in[3];

  float* out  = (float*)d_out;
  float* attn = out + (size_t)kB * kHW * kC;
  float* weT  = (float*)d_ws;

  we_proj_kernel<<<dim3(4, kB), 512, 0, stream>>>(emb, K, bias, weT);
  attn_kernel<<<dim3(kC / 64, kB), 256, 0, stream>>>(wc, weT, out, attn);
}

// Round 6
// 143.761 us; speedup vs baseline: 4.7443x; 4.7443x over previous
//
#include <hip/hip_runtime.h>

// ChannelAttention on MI355X (gfx950)
// B=128, HW=256, C=1024, S=32, EMB=256, IDF=256(==HW)
//
// out[b,p,c] = sum_s we[b,s,p] * softmax_s( sum_p' wc[b,p',c] * we[b,s,p'] )
// attn[b,c,s] = softmax probabilities
// d_out: out (128*256*1024 f32) then attn (128*1024*32 f32)
// d_ws : weT[b][p][s] (4 MB)
//
// R5: back to R0's fully-coalesced c-per-thread layout; the wave-uniform
// weT operand now lives in LDS (32 KB tile staged once per block) and is
// read via same-address ds_read_b128 broadcasts — conflict-free, on the
// LDS pipe, overlapping VALU FMAs. This avoids all three failed data
// paths: scalar-cache chains (R0/R2/R3), broadcast VMEM (R1), and
// shredded coalescing (R4).

namespace {
constexpr int kB  = 128;
constexpr int kHW = 256;
constexpr int kC  = 1024;
constexpr int kS  = 32;
constexpr int kE  = 256;
}

// weT[b][p][s] = bias[p] + sum_e emb[b][s][e] * K[e][p]
// grid (4,128): blockIdx.x = s-octet; 256 thr = p. emb tile transposed in LDS.
__global__ __launch_bounds__(256) void we_proj_kernel(
    const float* __restrict__ emb, const float* __restrict__ K,
    const float* __restrict__ bias, float* __restrict__ weT) {
  const int b  = blockIdx.y;
  const int sq = blockIdx.x;
  const int p  = threadIdx.x;

  __shared__ float embS[kE][8];   // embS[e][j] = emb[b][sq*8+j][e], 8 KB

  {  // stage transposed (one-time; coalesced global reads)
    const float* src = emb + (size_t)b * kS * kE + (size_t)sq * 8 * kE;
    const int j  = threadIdx.x >> 5;        // 0..7 (s within octet)
    const int e4 = (threadIdx.x & 31) * 8;  // 8 e per thread
#pragma unroll
    for (int u = 0; u < 8; ++u)
      embS[e4 + u][j] = src[j * kE + e4 + u];
  }
  __syncthreads();

  float acc[8];
#pragma unroll
  for (int j = 0; j < 8; ++j) acc[j] = 0.f;

#pragma unroll 4
  for (int e = 0; e < kE; ++e) {
    const float kv = K[e * kHW + p];        // lane-coalesced 1KB/wave
    const float4 e0 = *(const float4*)&embS[e][0];   // uniform broadcast
    const float4 e1 = *(const float4*)&embS[e][4];
    acc[0] = fmaf(e0.x, kv, acc[0]);
    acc[1] = fmaf(e0.y, kv, acc[1]);
    acc[2] = fmaf(e0.z, kv, acc[2]);
    acc[3] = fmaf(e0.w, kv, acc[3]);
    acc[4] = fmaf(e1.x, kv, acc[4]);
    acc[5] = fmaf(e1.y, kv, acc[5]);
    acc[6] = fmaf(e1.z, kv, acc[6]);
    acc[7] = fmaf(e1.w, kv, acc[7]);
  }

  const float bv = bias[p];
  float4* dst = (float4*)(weT + ((size_t)b * kHW + p) * kS + sq * 8);
  dst[0] = make_float4(acc[0] + bv, acc[1] + bv, acc[2] + bv, acc[3] + bv);
  dst[1] = make_float4(acc[4] + bv, acc[5] + bv, acc[6] + bv, acc[7] + bv);
}

// grid (4,128), 256 thr: thread owns channel c; weT[b] tile in LDS.
__global__ __launch_bounds__(256) void attn_kernel(
    const float* __restrict__ wc, const float* __restrict__ weT,
    float* __restrict__ out, float* __restrict__ attn_out) {
  const int b = blockIdx.y;
  const int c = blockIdx.x * 256 + threadIdx.x;
  const float* wcb  = wc  + (size_t)b * kHW * kC;

  __shared__ float weS[kHW][kS];   // 32 KB

  {  // stage weT[b] (32 KB) coalesced: 1KB per wave-instr
    const float4* src = (const float4*)(weT + (size_t)b * kHW * kS);
    float4* dst = (float4*)&weS[0][0];
#pragma unroll
    for (int q = 0; q < 8; ++q)
      dst[q * 256 + threadIdx.x] = src[q * 256 + threadIdx.x];
  }
  __syncthreads();

  // ---- Phase A: logits[s] = sum_p wc[p][c] * weS[p][s] ----
  float acc[kS];
#pragma unroll
  for (int s = 0; s < kS; ++s) acc[s] = 0.f;

#pragma unroll 4
  for (int p = 0; p < kHW; ++p) {
    const float w = wcb[(size_t)p * kC + c];        // coalesced 1KB/wave
    const float4* wrow = (const float4*)&weS[p][0]; // uniform broadcast b128
#pragma unroll
    for (int q = 0; q < 8; ++q) {
      const float4 t = wrow[q];
      acc[q * 4 + 0] = fmaf(t.x, w, acc[q * 4 + 0]);
      acc[q * 4 + 1] = fmaf(t.y, w, acc[q * 4 + 1]);
      acc[q * 4 + 2] = fmaf(t.z, w, acc[q * 4 + 2]);
      acc[q * 4 + 3] = fmaf(t.w, w, acc[q * 4 + 3]);
    }
  }

  // ---- softmax over s (per-thread, in registers) ----
  float m = acc[0];
#pragma unroll
  for (int s = 1; s < kS; ++s) m = fmaxf(m, acc[s]);
  float sum = 0.f;
#pragma unroll
  for (int s = 0; s < kS; ++s) {
    acc[s] = __expf(acc[s] - m);
    sum += acc[s];
  }
  const float inv = 1.0f / sum;
#pragma unroll
  for (int s = 0; s < kS; ++s) acc[s] *= inv;

  // ---- attn[b][c][0..31]: 128B contiguous per thread ----
  float4* ap = (float4*)(attn_out + ((size_t)b * kC + c) * kS);
#pragma unroll
  for (int s4 = 0; s4 < kS / 4; ++s4)
    ap[s4] = make_float4(acc[4 * s4], acc[4 * s4 + 1],
                         acc[4 * s4 + 2], acc[4 * s4 + 3]);

  // ---- Phase B: out[p][c] = sum_s weS[p][s] * prob[s] ----
  float* outb = out + (size_t)b * kHW * kC;
#pragma unroll 4
  for (int p = 0; p < kHW; ++p) {
    const float4* wrow = (const float4*)&weS[p][0];
    float o0 = 0.f, o1 = 0.f, o2 = 0.f, o3 = 0.f;
#pragma unroll
    for (int q = 0; q < 8; ++q) {
      const float4 t = wrow[q];
      o0 = fmaf(t.x, acc[q * 4 + 0], o0);
      o1 = fmaf(t.y, acc[q * 4 + 1], o1);
      o2 = fmaf(t.z, acc[q * 4 + 2], o2);
      o3 = fmaf(t.w, acc[q * 4 + 3], o3);
    }
    outb[(size_t)p * kC + c] = (o0 + o1) + (o2 + o3);  // coalesced store
  }
}

extern "C" void kernel_launch(void* const* d_in, const int* in_sizes, int n_in,
                              void* d_out, int out_size, void* d_ws, size_t ws_size,
                              hipStream_t stream) {
  const float* wc   = (const float*)d_in[0];
  const float* emb  = (const float*)d_in[1];
  const float* K    = (const float*)d_in[2];
  const float* bias = (const float*)d_in[3];

  float* out  = (float*)d_out;
  float* attn = out + (size_t)kB * kHW * kC;
  float* weT  = (float*)d_ws;

  we_proj_kernel<<<dim3(4, kB), 256, 0, stream>>>(emb, K, bias, weT);
  attn_kernel<<<dim3(4, kB), 256, 0, stream>>>(wc, weT, out, attn);
}

// Round 7
// 134.027 us; speedup vs baseline: 5.0888x; 1.0726x over previous
//
#include <hip/hip_runtime.h>

// ChannelAttention on MI355X (gfx950)
// B=128, HW=256, C=1024, S=32, EMB=256, IDF=256(==HW)
//
// out[b,p,c] = sum_s we[b,s,p] * softmax_s( sum_p' wc[b,p',c] * we[b,s,p'] )
// attn[b,c,s] = softmax probabilities
// d_out: out (128*256*1024 f32) then attn (128*1024*32 f32)
// d_ws : weT[b][p][s] (4 MB)
//
// R6 = R5 (c-per-thread, weT tile in LDS, ds_read_b128 broadcasts) +
// R3's explicit 16-deep ping-pong prefetch of wc in phase A: 16 loads in
// flight issued BEFORE consuming the previous 16 (512 FMA = 1024 cyc cover
// vs ~900 cyc HBM latency). R3 proved the pipeline; R5 proved the consume
// path; this combines them.

namespace {
constexpr int kB  = 128;
constexpr int kHW = 256;
constexpr int kC  = 1024;
constexpr int kS  = 32;
constexpr int kE  = 256;
}

// weT[b][p][s] = bias[p] + sum_e emb[b][s][e] * K[e][p]
// grid (4,128): blockIdx.x = s-octet; 256 thr = p. emb tile transposed in LDS.
__global__ __launch_bounds__(256) void we_proj_kernel(
    const float* __restrict__ emb, const float* __restrict__ K,
    const float* __restrict__ bias, float* __restrict__ weT) {
  const int b  = blockIdx.y;
  const int sq = blockIdx.x;
  const int p  = threadIdx.x;

  __shared__ float embS[kE][8];   // embS[e][j] = emb[b][sq*8+j][e], 8 KB

  {  // stage transposed (one-time; coalesced global reads)
    const float* src = emb + (size_t)b * kS * kE + (size_t)sq * 8 * kE;
    const int j  = threadIdx.x >> 5;        // 0..7 (s within octet)
    const int e4 = (threadIdx.x & 31) * 8;  // 8 e per thread
#pragma unroll
    for (int u = 0; u < 8; ++u)
      embS[e4 + u][j] = src[j * kE + e4 + u];
  }
  __syncthreads();

  float acc[8];
#pragma unroll
  for (int j = 0; j < 8; ++j) acc[j] = 0.f;

#pragma unroll 4
  for (int e = 0; e < kE; ++e) {
    const float kv = K[e * kHW + p];        // lane-coalesced 1KB/wave
    const float4 e0 = *(const float4*)&embS[e][0];   // uniform broadcast
    const float4 e1 = *(const float4*)&embS[e][4];
    acc[0] = fmaf(e0.x, kv, acc[0]);
    acc[1] = fmaf(e0.y, kv, acc[1]);
    acc[2] = fmaf(e0.z, kv, acc[2]);
    acc[3] = fmaf(e0.w, kv, acc[3]);
    acc[4] = fmaf(e1.x, kv, acc[4]);
    acc[5] = fmaf(e1.y, kv, acc[5]);
    acc[6] = fmaf(e1.z, kv, acc[6]);
    acc[7] = fmaf(e1.w, kv, acc[7]);
  }

  const float bv = bias[p];
  float4* dst = (float4*)(weT + ((size_t)b * kHW + p) * kS + sq * 8);
  dst[0] = make_float4(acc[0] + bv, acc[1] + bv, acc[2] + bv, acc[3] + bv);
  dst[1] = make_float4(acc[4] + bv, acc[5] + bv, acc[6] + bv, acc[7] + bv);
}

// grid (4,128), 256 thr: thread owns channel c; weT[b] tile in LDS.
__global__ __launch_bounds__(256) void attn_kernel(
    const float* __restrict__ wc, const float* __restrict__ weT,
    float* __restrict__ out, float* __restrict__ attn_out) {
  const int b = blockIdx.y;
  const int c = blockIdx.x * 256 + threadIdx.x;
  const float* wcb = wc + (size_t)b * kHW * kC;
  const float* wcc = wcb + c;               // wc[p][c] = wcc[p*kC]

  __shared__ float weS[kHW][kS];   // 32 KB

  {  // stage weT[b] (32 KB) coalesced
    const float4* src = (const float4*)(weT + (size_t)b * kHW * kS);
    float4* dst = (float4*)&weS[0][0];
#pragma unroll
    for (int q = 0; q < 8; ++q)
      dst[q * 256 + threadIdx.x] = src[q * 256 + threadIdx.x];
  }
  __syncthreads();

  // ---- Phase A: logits[s] = sum_p wc[p][c] * weS[p][s], ping-pong 16-deep
  float acc[kS];
#pragma unroll
  for (int s = 0; s < kS; ++s) acc[s] = 0.f;

  float wA[16], wB[16];
#pragma unroll
  for (int u = 0; u < 16; ++u)                  // prologue: group 0 in flight
    wA[u] = wcc[(size_t)u * kC];

#pragma unroll 1
  for (int g = 0; g < 16; g += 2) {
    const int pA = g * 16, pB = pA + 16, pN = pA + 32;
    // issue group g+1 loads, then consume group g
#pragma unroll
    for (int u = 0; u < 16; ++u)
      wB[u] = wcc[(size_t)(pB + u) * kC];
#pragma unroll
    for (int u = 0; u < 16; ++u) {
      const float4* wrow = (const float4*)&weS[pA + u][0];  // broadcast b128
      const float wv = wA[u];
#pragma unroll
      for (int q = 0; q < 8; ++q) {
        const float4 t = wrow[q];
        acc[q * 4 + 0] = fmaf(t.x, wv, acc[q * 4 + 0]);
        acc[q * 4 + 1] = fmaf(t.y, wv, acc[q * 4 + 1]);
        acc[q * 4 + 2] = fmaf(t.z, wv, acc[q * 4 + 2]);
        acc[q * 4 + 3] = fmaf(t.w, wv, acc[q * 4 + 3]);
      }
    }
    // issue group g+2 loads (guarded), then consume group g+1
    if (pN < kHW) {
#pragma unroll
      for (int u = 0; u < 16; ++u)
        wA[u] = wcc[(size_t)(pN + u) * kC];
    }
#pragma unroll
    for (int u = 0; u < 16; ++u) {
      const float4* wrow = (const float4*)&weS[pB + u][0];
      const float wv = wB[u];
#pragma unroll
      for (int q = 0; q < 8; ++q) {
        const float4 t = wrow[q];
        acc[q * 4 + 0] = fmaf(t.x, wv, acc[q * 4 + 0]);
        acc[q * 4 + 1] = fmaf(t.y, wv, acc[q * 4 + 1]);
        acc[q * 4 + 2] = fmaf(t.z, wv, acc[q * 4 + 2]);
        acc[q * 4 + 3] = fmaf(t.w, wv, acc[q * 4 + 3]);
      }
    }
  }

  // ---- softmax over s (per-thread, in registers) ----
  float m = acc[0];
#pragma unroll
  for (int s = 1; s < kS; ++s) m = fmaxf(m, acc[s]);
  float sum = 0.f;
#pragma unroll
  for (int s = 0; s < kS; ++s) {
    acc[s] = __expf(acc[s] - m);
    sum += acc[s];
  }
  const float inv = 1.0f / sum;
#pragma unroll
  for (int s = 0; s < kS; ++s) acc[s] *= inv;

  // ---- attn[b][c][0..31]: 128B contiguous per thread ----
  float4* ap = (float4*)(attn_out + ((size_t)b * kC + c) * kS);
#pragma unroll
  for (int s4 = 0; s4 < kS / 4; ++s4)
    ap[s4] = make_float4(acc[4 * s4], acc[4 * s4 + 1],
                         acc[4 * s4 + 2], acc[4 * s4 + 3]);

  // ---- Phase B: out[p][c] = sum_s weS[p][s] * prob[s] ----
  // no global loads in the loop; stores are fire-and-forget
  float* outb = out + (size_t)b * kHW * kC;
#pragma unroll 4
  for (int p = 0; p < kHW; ++p) {
    const float4* wrow = (const float4*)&weS[p][0];
    float o0 = 0.f, o1 = 0.f, o2 = 0.f, o3 = 0.f;
#pragma unroll
    for (int q = 0; q < 8; ++q) {
      const float4 t = wrow[q];
      o0 = fmaf(t.x, acc[q * 4 + 0], o0);
      o1 = fmaf(t.y, acc[q * 4 + 1], o1);
      o2 = fmaf(t.z, acc[q * 4 + 2], o2);
      o3 = fmaf(t.w, acc[q * 4 + 3], o3);
    }
    outb[(size_t)p * kC + c] = (o0 + o1) + (o2 + o3);  // coalesced store
  }
}

extern "C" void kernel_launch(void* const* d_in, const int* in_sizes, int n_in,
                              void* d_out, int out_size, void* d_ws, size_t ws_size,
                              hipStream_t stream) {
  const float* wc   = (const float*)d_in[0];
  const float* emb  = (const float*)d_in[1];
  const float* K    = (const float*)d_in[2];
  const float* bias = (const float*)d_in[3];

  float* out  = (float*)d_out;
  float* attn = out + (size_t)kB * kHW * kC;
  float* weT  = (float*)d_ws;

  we_proj_kernel<<<dim3(4, kB), 256, 0, stream>>>(emb, K, bias, weT);
  attn_kernel<<<dim3(4, kB), 256, 0, stream>>>(wc, weT, out, attn);
}

// Round 8
// 121.561 us; speedup vs baseline: 5.6106x; 1.1025x over previous
//
#include <hip/hip_runtime.h>

// ChannelAttention on MI355X (gfx950)
// B=128, HW=256, C=1024, S=32, EMB=256, IDF=256(==HW)
//
// out[b,p,c] = sum_s we[b,s,p] * softmax_s( sum_p' wc[b,p',c] * we[b,s,p'] )
// attn[b,c,s] = softmax probabilities
// d_out: out (128*256*1024 f32) then attn (128*1024*32 f32)
// d_ws : weT[b][p][s] (4 MB)
//
// R7 = R6 + 2 channels per thread (c, c+256). R6 accounting showed VALU
// (27us) + LDS-broadcast pipe (<=41us) + HBM (36us) were SERIALIZING at
// 2 waves/SIMD. Doubling per-thread work halves the per-CU LDS-broadcast
// and wave count while keeping VALU constant: LDS demand drops 4x vs
// VALU -> hides under FMA stream; 2048-cyc prefetch cover per group.
// Grid (2,128) = 256 blocks = 1 block/CU; VGPR is free (grid-capped occ).

namespace {
constexpr int kB  = 128;
constexpr int kHW = 256;
constexpr int kC  = 1024;
constexpr int kS  = 32;
constexpr int kE  = 256;
}

// weT[b][p][s] = bias[p] + sum_e emb[b][s][e] * K[e][p]
__global__ __launch_bounds__(256) void we_proj_kernel(
    const float* __restrict__ emb, const float* __restrict__ K,
    const float* __restrict__ bias, float* __restrict__ weT) {
  const int b  = blockIdx.y;
  const int sq = blockIdx.x;
  const int p  = threadIdx.x;

  __shared__ float embS[kE][8];   // embS[e][j] = emb[b][sq*8+j][e], 8 KB

  {
    const float* src = emb + (size_t)b * kS * kE + (size_t)sq * 8 * kE;
    const int j  = threadIdx.x >> 5;
    const int e4 = (threadIdx.x & 31) * 8;
#pragma unroll
    for (int u = 0; u < 8; ++u)
      embS[e4 + u][j] = src[j * kE + e4 + u];
  }
  __syncthreads();

  float acc[8];
#pragma unroll
  for (int j = 0; j < 8; ++j) acc[j] = 0.f;

#pragma unroll 4
  for (int e = 0; e < kE; ++e) {
    const float kv = K[e * kHW + p];
    const float4 e0 = *(const float4*)&embS[e][0];
    const float4 e1 = *(const float4*)&embS[e][4];
    acc[0] = fmaf(e0.x, kv, acc[0]);
    acc[1] = fmaf(e0.y, kv, acc[1]);
    acc[2] = fmaf(e0.z, kv, acc[2]);
    acc[3] = fmaf(e0.w, kv, acc[3]);
    acc[4] = fmaf(e1.x, kv, acc[4]);
    acc[5] = fmaf(e1.y, kv, acc[5]);
    acc[6] = fmaf(e1.z, kv, acc[6]);
    acc[7] = fmaf(e1.w, kv, acc[7]);
  }

  const float bv = bias[p];
  float4* dst = (float4*)(weT + ((size_t)b * kHW + p) * kS + sq * 8);
  dst[0] = make_float4(acc[0] + bv, acc[1] + bv, acc[2] + bv, acc[3] + bv);
  dst[1] = make_float4(acc[4] + bv, acc[5] + bv, acc[6] + bv, acc[7] + bv);
}

// grid (2,128), 256 thr: thread owns channels c0=bx*512+tid and c1=c0+256.
__global__ __launch_bounds__(256, 1) void attn_kernel(
    const float* __restrict__ wc, const float* __restrict__ weT,
    float* __restrict__ out, float* __restrict__ attn_out) {
  const int b  = blockIdx.y;
  const int c0 = blockIdx.x * 512 + threadIdx.x;
  const float* wcb = wc + (size_t)b * kHW * kC;
  const float* wc0 = wcb + c0;
  const float* wc1 = wcb + c0 + 256;

  __shared__ float weS[kHW][kS];   // 32 KB

  {
    const float4* src = (const float4*)(weT + (size_t)b * kHW * kS);
    float4* dst = (float4*)&weS[0][0];
#pragma unroll
    for (int q = 0; q < 8; ++q)
      dst[q * 256 + threadIdx.x] = src[q * 256 + threadIdx.x];
  }
  __syncthreads();

  // ---- Phase A: two logit rows, 16-p ping-pong prefetch ----
  float a0[kS], a1[kS];
#pragma unroll
  for (int s = 0; s < kS; ++s) { a0[s] = 0.f; a1[s] = 0.f; }

  float wA0[16], wA1[16], wB0[16], wB1[16];
#pragma unroll
  for (int u = 0; u < 16; ++u) {
    wA0[u] = wc0[(size_t)u * kC];
    wA1[u] = wc1[(size_t)u * kC];
  }

#pragma unroll 1
  for (int g = 0; g < 16; g += 2) {
    const int pA = g * 16, pB = pA + 16, pN = pA + 32;
#pragma unroll
    for (int u = 0; u < 16; ++u) {
      wB0[u] = wc0[(size_t)(pB + u) * kC];
      wB1[u] = wc1[(size_t)(pB + u) * kC];
    }
#pragma unroll
    for (int u = 0; u < 16; ++u) {
      const float4* wrow = (const float4*)&weS[pA + u][0];
      const float v0 = wA0[u], v1 = wA1[u];
#pragma unroll
      for (int q = 0; q < 8; ++q) {
        const float4 t = wrow[q];
        a0[q * 4 + 0] = fmaf(t.x, v0, a0[q * 4 + 0]);
        a0[q * 4 + 1] = fmaf(t.y, v0, a0[q * 4 + 1]);
        a0[q * 4 + 2] = fmaf(t.z, v0, a0[q * 4 + 2]);
        a0[q * 4 + 3] = fmaf(t.w, v0, a0[q * 4 + 3]);
        a1[q * 4 + 0] = fmaf(t.x, v1, a1[q * 4 + 0]);
        a1[q * 4 + 1] = fmaf(t.y, v1, a1[q * 4 + 1]);
        a1[q * 4 + 2] = fmaf(t.z, v1, a1[q * 4 + 2]);
        a1[q * 4 + 3] = fmaf(t.w, v1, a1[q * 4 + 3]);
      }
    }
    if (pN < kHW) {
#pragma unroll
      for (int u = 0; u < 16; ++u) {
        wA0[u] = wc0[(size_t)(pN + u) * kC];
        wA1[u] = wc1[(size_t)(pN + u) * kC];
      }
    }
#pragma unroll
    for (int u = 0; u < 16; ++u) {
      const float4* wrow = (const float4*)&weS[pB + u][0];
      const float v0 = wB0[u], v1 = wB1[u];
#pragma unroll
      for (int q = 0; q < 8; ++q) {
        const float4 t = wrow[q];
        a0[q * 4 + 0] = fmaf(t.x, v0, a0[q * 4 + 0]);
        a0[q * 4 + 1] = fmaf(t.y, v0, a0[q * 4 + 1]);
        a0[q * 4 + 2] = fmaf(t.z, v0, a0[q * 4 + 2]);
        a0[q * 4 + 3] = fmaf(t.w, v0, a0[q * 4 + 3]);
        a1[q * 4 + 0] = fmaf(t.x, v1, a1[q * 4 + 0]);
        a1[q * 4 + 1] = fmaf(t.y, v1, a1[q * 4 + 1]);
        a1[q * 4 + 2] = fmaf(t.z, v1, a1[q * 4 + 2]);
        a1[q * 4 + 3] = fmaf(t.w, v1, a1[q * 4 + 3]);
      }
    }
  }

  // ---- softmax (both rows, per-thread) ----
  float m0 = a0[0], m1 = a1[0];
#pragma unroll
  for (int s = 1; s < kS; ++s) { m0 = fmaxf(m0, a0[s]); m1 = fmaxf(m1, a1[s]); }
  float s0 = 0.f, s1 = 0.f;
#pragma unroll
  for (int s = 0; s < kS; ++s) {
    a0[s] = __expf(a0[s] - m0); s0 += a0[s];
    a1[s] = __expf(a1[s] - m1); s1 += a1[s];
  }
  const float i0 = 1.0f / s0, i1 = 1.0f / s1;
#pragma unroll
  for (int s = 0; s < kS; ++s) { a0[s] *= i0; a1[s] *= i1; }

  // ---- attn rows (128B contiguous per channel) ----
  {
    float4* ap0 = (float4*)(attn_out + ((size_t)b * kC + c0) * kS);
    float4* ap1 = (float4*)(attn_out + ((size_t)b * kC + c0 + 256) * kS);
#pragma unroll
    for (int q = 0; q < 8; ++q) {
      ap0[q] = make_float4(a0[4 * q], a0[4 * q + 1], a0[4 * q + 2], a0[4 * q + 3]);
      ap1[q] = make_float4(a1[4 * q], a1[4 * q + 1], a1[4 * q + 2], a1[4 * q + 3]);
    }
  }

  // ---- Phase B: out[p][c0], out[p][c0+256] ----
  float* ob0 = out + (size_t)b * kHW * kC + c0;
  float* ob1 = ob0 + 256;
#pragma unroll 2
  for (int p = 0; p < kHW; ++p) {
    const float4* wrow = (const float4*)&weS[p][0];
    float x0 = 0.f, x1 = 0.f, x2 = 0.f, x3 = 0.f;
    float y0 = 0.f, y1 = 0.f, y2 = 0.f, y3 = 0.f;
#pragma unroll
    for (int q = 0; q < 8; ++q) {
      const float4 t = wrow[q];
      x0 = fmaf(t.x, a0[q * 4 + 0], x0);
      x1 = fmaf(t.y, a0[q * 4 + 1], x1);
      x2 = fmaf(t.z, a0[q * 4 + 2], x2);
      x3 = fmaf(t.w, a0[q * 4 + 3], x3);
      y0 = fmaf(t.x, a1[q * 4 + 0], y0);
      y1 = fmaf(t.y, a1[q * 4 + 1], y1);
      y2 = fmaf(t.z, a1[q * 4 + 2], y2);
      y3 = fmaf(t.w, a1[q * 4 + 3], y3);
    }
    ob0[(size_t)p * kC] = (x0 + x1) + (x2 + x3);
    ob1[(size_t)p * kC] = (y0 + y1) + (y2 + y3);
  }
}

extern "C" void kernel_launch(void* const* d_in, const int* in_sizes, int n_in,
                              void* d_out, int out_size, void* d_ws, size_t ws_size,
                              hipStream_t stream) {
  const float* wc   = (const float*)d_in[0];
  const float* emb  = (const float*)d_in[1];
  const float* K    = (const float*)d_in[2];
  const float* bias = (const float*)d_in[3];

  float* out  = (float*)d_out;
  float* attn = out + (size_t)kB * kHW * kC;
  float* weT  = (float*)d_ws;

  we_proj_kernel<<<dim3(4, kB), 256, 0, stream>>>(emb, K, bias, weT);
  attn_kernel<<<dim3(2, kB), 256, 0, stream>>>(wc, weT, out, attn);
}

// Round 9
// 83.125 us; speedup vs baseline: 8.2050x; 1.4624x over previous
//
#include <hip/hip_runtime.h>

// ChannelAttention on MI355X (gfx950) — R8: split-bf16 MFMA
// B=128, HW=256, C=1024, S=32, EMB=256, IDF=256(==HW)
//
// out[b,p,c] = sum_s we[b,s,p] * softmax_s( sum_p' wc[b,p',c] * we[b,s,p'] )
// attn[b,c,s] = softmax probabilities
// d_out: out (128*256*1024 f32) then attn (128*1024*32 f32)
// d_ws : weT hi/lo bf16 [b][p][s] (2 MB + 2 MB)
//
// R0-R7 lesson: f32 VALU path converges to ~120us (27us FMA floor + LDS
// broadcast + HBM refuse to overlap at achievable occupancy). Move both
// matmuls to the MFMA pipe with 3-term split-bf16 (hi*hi + hi*lo + lo*hi,
// ~2^-15 rel err). mfma_f32_16x16x32_bf16 layouts (m89-verified):
//   A[M][K]: lane row M=l&15, k=(l>>4)*8+i ; B[K][N]: col N=l&15, same k
//   C/D: col=l&15, row=(l>>4)*4+reg
// Phase A: D[c][s] = wc^T(A, from global, split in-reg) x weT(B, LDS)
// Phase B: D[p][c] = weT(A, LDS b128 frags) x P(B, per-wave LDS, split)

typedef float  f32x4  __attribute__((ext_vector_type(4)));
typedef short  bf16x8 __attribute__((ext_vector_type(8)));

namespace {
constexpr int kB = 128, kHW = 256, kC = 1024, kS = 32, kE = 256;
constexpr int WR = 40;   // LDS row stride in shorts (80B: 16B-aligned, bank-spread)
}

__device__ inline ushort f2bf(float x) {             // f32 -> bf16 RNE
  unsigned u = __float_as_uint(x);
  u += 0x7fffu + ((u >> 16) & 1u);
  return (ushort)(u >> 16);
}
__device__ inline float bf2f(ushort h) { return __uint_as_float(((unsigned)h) << 16); }

#define MFMA16(A, Bf, Cv) __builtin_amdgcn_mfma_f32_16x16x32_bf16((A), (Bf), (Cv), 0, 0, 0)

// weT[b][p][s] = bias[p] + sum_e emb[b][s][e]*K[e][p]; output split bf16 hi/lo.
__global__ __launch_bounds__(256) void we_proj_kernel(
    const float* __restrict__ emb, const float* __restrict__ K,
    const float* __restrict__ bias, ushort* __restrict__ wTh,
    ushort* __restrict__ wTl) {
  const int b  = blockIdx.y;
  const int sq = blockIdx.x;
  const int p  = threadIdx.x;

  __shared__ float embS[kE][8];   // embS[e][j] = emb[b][sq*8+j][e]
  {
    const float* src = emb + (size_t)b * kS * kE + (size_t)sq * 8 * kE;
    const int j  = threadIdx.x >> 5;
    const int e4 = (threadIdx.x & 31) * 8;
#pragma unroll
    for (int u = 0; u < 8; ++u) embS[e4 + u][j] = src[j * kE + e4 + u];
  }
  __syncthreads();

  float acc[8];
#pragma unroll
  for (int j = 0; j < 8; ++j) acc[j] = 0.f;

#pragma unroll 4
  for (int e = 0; e < kE; ++e) {
    const float kv = K[e * kHW + p];
    const float4 e0 = *(const float4*)&embS[e][0];
    const float4 e1 = *(const float4*)&embS[e][4];
    acc[0] = fmaf(e0.x, kv, acc[0]); acc[1] = fmaf(e0.y, kv, acc[1]);
    acc[2] = fmaf(e0.z, kv, acc[2]); acc[3] = fmaf(e0.w, kv, acc[3]);
    acc[4] = fmaf(e1.x, kv, acc[4]); acc[5] = fmaf(e1.y, kv, acc[5]);
    acc[6] = fmaf(e1.z, kv, acc[6]); acc[7] = fmaf(e1.w, kv, acc[7]);
  }

  const float bv = bias[p];
  bf16x8 hv, lv;
#pragma unroll
  for (int j = 0; j < 8; ++j) {
    const float x = acc[j] + bv;
    const ushort h = f2bf(x);
    hv[j] = (short)h;
    lv[j] = (short)f2bf(x - bf2f(h));
  }
  const size_t o = ((size_t)b * kHW + p) * kS + sq * 8;
  *(bf16x8*)(wTh + o) = hv;
  *(bf16x8*)(wTl + o) = lv;
}

// grid (4,128), 256 thr = 4 waves; block: one b, 256 channels; wave: 64 c's.
__global__ __launch_bounds__(256, 2) void attn_kernel(
    const float* __restrict__ wc, const ushort* __restrict__ wTh,
    const ushort* __restrict__ wTl, float* __restrict__ out,
    float* __restrict__ attn_out) {
  const int b    = blockIdx.y;
  const int cb   = blockIdx.x * 256;
  const int tid  = threadIdx.x;
  const int wave = tid >> 6, lane = tid & 63;
  const int lr   = lane & 15, lg = lane >> 4;

  __shared__ ushort wH[kHW][WR], wL[kHW][WR];   // weT hi/lo  (2 x 20KB)
  __shared__ ushort pH[256][WR], pL[256][WR];   // P   hi/lo  (2 x 20KB)

  {  // stage weT[b] hi/lo: thread owns row p=tid (64B contiguous per array)
    const bf16x8* sh = (const bf16x8*)(wTh + ((size_t)b * kHW + tid) * kS);
    const bf16x8* sl = (const bf16x8*)(wTl + ((size_t)b * kHW + tid) * kS);
#pragma unroll
    for (int k = 0; k < 4; ++k) {
      *(bf16x8*)&wH[tid][k * 8] = sh[k];
      *(bf16x8*)&wL[tid][k * 8] = sl[k];
    }
  }
  __syncthreads();

  const float* wcb = wc + (size_t)b * kHW * kC;
  const int c0 = cb + wave * 64;

  // ---- Phase A: D[c][s] over 4 M-tiles (c) x 2 N-tiles (s), K=256 ----
  f32x4 acc[4][2];
#pragma unroll
  for (int m = 0; m < 4; ++m)
#pragma unroll
    for (int n = 0; n < 2; ++n) acc[m][n] = (f32x4){0.f, 0.f, 0.f, 0.f};

  float avC[8], avN[8];
#pragma unroll
  for (int i = 0; i < 8; ++i)              // prologue: (kt=0, m=0)
    avC[i] = wcb[(size_t)(lg * 8 + i) * kC + c0 + lr];

#pragma unroll 1
  for (int kt = 0; kt < 8; ++kt) {
    bf16x8 bh[2], bl[2];
#pragma unroll
    for (int n = 0; n < 2; ++n)
#pragma unroll
      for (int j = 0; j < 8; ++j) {
        const int row = kt * 32 + lg * 8 + j;
        bh[n][j] = (short)wH[row][n * 16 + lr];
        bl[n][j] = (short)wL[row][n * 16 + lr];
      }
#pragma unroll
    for (int m = 0; m < 4; ++m) {
      const int mn  = (m + 1) & 3;            // prefetch next (kt,m)
      const int ktn = (m == 3) ? kt + 1 : kt;
      if (!(kt == 7 && m == 3)) {
#pragma unroll
        for (int i = 0; i < 8; ++i)
          avN[i] = wcb[(size_t)(ktn * 32 + lg * 8 + i) * kC + c0 + mn * 16 + lr];
      }
      bf16x8 ah, al;
#pragma unroll
      for (int i = 0; i < 8; ++i) {
        const ushort h = f2bf(avC[i]);
        ah[i] = (short)h;
        al[i] = (short)f2bf(avC[i] - bf2f(h));
      }
#pragma unroll
      for (int n = 0; n < 2; ++n) {
        acc[m][n] = MFMA16(ah, bh[n], acc[m][n]);
        acc[m][n] = MFMA16(ah, bl[n], acc[m][n]);
        acc[m][n] = MFMA16(al, bh[n], acc[m][n]);
      }
#pragma unroll
      for (int i = 0; i < 8; ++i) avC[i] = avN[i];
    }
  }

  // ---- softmax over s (row c = c0 + m*16 + lg*4 + j; cols s=lr, s=16+lr)
  float* attnb = attn_out + ((size_t)b * kC + cb) * kS;
#pragma unroll
  for (int m = 0; m < 4; ++m) {
#pragma unroll
    for (int j = 0; j < 4; ++j) {
      float v0 = acc[m][0][j], v1 = acc[m][1][j];
      float mx = fmaxf(v0, v1);
      mx = fmaxf(mx, __shfl_xor(mx, 1));
      mx = fmaxf(mx, __shfl_xor(mx, 2));
      mx = fmaxf(mx, __shfl_xor(mx, 4));
      mx = fmaxf(mx, __shfl_xor(mx, 8));
      float e0 = __expf(v0 - mx), e1 = __expf(v1 - mx);
      float sm = e0 + e1;
      sm += __shfl_xor(sm, 1); sm += __shfl_xor(sm, 2);
      sm += __shfl_xor(sm, 4); sm += __shfl_xor(sm, 8);
      const float inv = 1.f / sm;
      e0 *= inv; e1 *= inv;
      const int cL = wave * 64 + m * 16 + lg * 4 + j;
      attnb[(size_t)cL * kS + lr]      = e0;    // attn[b][c][s]
      attnb[(size_t)cL * kS + 16 + lr] = e1;
      const ushort h0 = f2bf(e0);
      pH[cL][lr] = h0;           pL[cL][lr] = f2bf(e0 - bf2f(h0));
      const ushort h1 = f2bf(e1);
      pH[cL][16 + lr] = h1;      pL[cL][16 + lr] = f2bf(e1 - bf2f(h1));
    }
  }
  // P is wave-local (each wave reads only its own 64 c rows): no barrier.

  // ---- Phase B: D[p][c] = weT(A) x P(B), K=32, 16 p-tiles x 4 c-tiles ----
  bf16x8 pbh[4], pbl[4];
#pragma unroll
  for (int n = 0; n < 4; ++n) {
    const int cL = wave * 64 + n * 16 + lr;   // B col = lane&15
    pbh[n] = *(const bf16x8*)&pH[cL][lg * 8]; // k = (l>>4)*8 + j
    pbl[n] = *(const bf16x8*)&pL[cL][lg * 8];
  }
  float* outb = out + (size_t)b * kHW * kC + cb;
#pragma unroll 1
  for (int pt = 0; pt < 16; ++pt) {
    const int pr = pt * 16 + lr;              // A row = lane&15
    const bf16x8 ah = *(const bf16x8*)&wH[pr][lg * 8];
    const bf16x8 al = *(const bf16x8*)&wL[pr][lg * 8];
#pragma unroll
    for (int n = 0; n < 4; ++n) {
      f32x4 o = (f32x4){0.f, 0.f, 0.f, 0.f};
      o = MFMA16(ah, pbh[n], o);
      o = MFMA16(ah, pbl[n], o);
      o = MFMA16(al, pbh[n], o);
      const int ccol = wave * 64 + n * 16 + lr;
#pragma unroll
      for (int j = 0; j < 4; ++j)
        outb[(size_t)(pt * 16 + lg * 4 + j) * kC + ccol] = o[j];
    }
  }
}

extern "C" void kernel_launch(void* const* d_in, const int* in_sizes, int n_in,
                              void* d_out, int out_size, void* d_ws, size_t ws_size,
                              hipStream_t stream) {
  const float* wc   = (const float*)d_in[0];
  const float* emb  = (const float*)d_in[1];
  const float* K    = (const float*)d_in[2];
  const float* bias = (const float*)d_in[3];

  float* out  = (float*)d_out;
  float* attn = out + (size_t)kB * kHW * kC;
  ushort* wTh = (ushort*)d_ws;                         // 2 MB
  ushort* wTl = wTh + (size_t)kB * kHW * kS;           // 2 MB

  we_proj_kernel<<<dim3(4, kB), 256, 0, stream>>>(emb, K, bias, wTh, wTl);
  attn_kernel<<<dim3(4, kB), 256, 0, stream>>>(wc, wTh, wTl, out, attn);
}